// Round 2
// baseline (478.557 us; speedup 1.0000x reference)
//
#include <hip/hip_runtime.h>
#include <hip/hip_bf16.h>

// EdgeEncoder: social-attention with relative-position-encoded keys/values.
// Algebraic folding:
//   k[i,j] = kbase[j] + W2k @ hid[i,j],   W2k = Wk @ W2 (128x64)
//   score  = q.kbase[j] + qw[i,hd].hid[i,j]
//   ctx    = sum_j attn*vbase[j] + W2v @ (sum_j attn*hid[i,j])
// Per-pair cost drops from ~82 kFLOP to ~1.3 kFLOP; total ~3 GFLOP.
//
// DTYPE-ADAPTIVE: device tensors may be bf16-converted or raw fp32 (harness
// ambiguity). Each kernel self-detects via a 64-word exponent-structure vote
// on node_features; both template variants launch, the wrong one exits.
//
// ws layout (bytes):  [0,32K)   W2KT fp32 [e][ch]   (Wk@W2 transposed)
//                     [32K,64K) W2VT fp32 [e][ch]
//                     [64K, 64K+2M)    KB bf16-pairs [s][j][cw]  kbase
//                     [64K+2M, 64K+4M) VB bf16-pairs             vbase
// requires ws_size >= 4,259,840 B.

#define SNUM 128
#define SCALE 0.17677669529663689f   // 1/sqrt(32)

typedef unsigned int u32;

__device__ __forceinline__ float bl(u32 u){ union{u32 x; float f;} c; c.x = u << 16; return c.f; }
__device__ __forceinline__ float bh(u32 u){ union{u32 x; float f;} c; c.x = u & 0xffff0000u; return c.f; }
__device__ __forceinline__ u32 pk(float a, float b){
  union{float f; u32 x;} ca, cb; ca.f = a; cb.f = b;
  u32 ua = (ca.x + 0x7fffu + ((ca.x >> 16) & 1u)) >> 16;   // RNE fp32->bf16
  u32 ub = (cb.x + 0x7fffu + ((cb.x >> 16) & 1u)) >> 16;
  return ua | (ub << 16);
}

// ---- dtype-adaptive loads: element-pair, scalar, 8-element group ----------
template<bool BF16>
__device__ __forceinline__ float2 ld2f(const void* p, int pairIdx){
  if (BF16){ u32 u = ((const u32*)p)[pairIdx]; return make_float2(bl(u), bh(u)); }
  return ((const float2*)p)[pairIdx];
}
template<bool BF16>
__device__ __forceinline__ float ld1f(const void* p, int i){
  if (BF16) return __bfloat162float(((const __hip_bfloat16*)p)[i]);
  return ((const float*)p)[i];
}
template<bool BF16>
__device__ __forceinline__ void ld8f(const void* p, int grp, float4& A, float4& B){
  if (BF16){
    uint4 u = ((const uint4*)p)[grp];
    A = make_float4(bl(u.x), bh(u.x), bl(u.y), bh(u.y));
    B = make_float4(bl(u.z), bh(u.z), bl(u.w), bh(u.w));
  } else {
    const float4* q = (const float4*)p;
    A = q[2 * grp]; B = q[2 * grp + 1];
  }
}
__device__ __forceinline__ float dot8(float4 wa, float4 wb, float4 f0, float4 f1, float acc){
  acc = fmaf(wa.x, f0.x, acc); acc = fmaf(wa.y, f0.y, acc);
  acc = fmaf(wa.z, f0.z, acc); acc = fmaf(wa.w, f0.w, acc);
  acc = fmaf(wb.x, f1.x, acc); acc = fmaf(wb.y, f1.y, acc);
  acc = fmaf(wb.z, f1.z, acc); acc = fmaf(wb.w, f1.w, acc);
  return acc;
}

// ---- device-side dtype sniff: bf16-packed pairs have a structured exponent
// field in the LOW 16 bits; fp32 low bits are random mantissa. --------------
__device__ __forceinline__ bool sniff_bf16(const u32* nf){
  u32 u = nf[threadIdx.x & 63];
  u32 e = (u >> 7) & 0xFFu;
  int hit = ((e >= 100u) && (e <= 140u)) || ((u & 0xFFFFu) == 0u);
  unsigned long long m = __ballot(hit);
  return __popcll(m) >= 40;
}

// ---------------- kernel 1: per-scene kbase/vbase + folded W2k/W2v ----------
template<bool BF16>
__global__ __launch_bounds__(256) void ee_setup(
    const void* __restrict__ nfp, const void* __restrict__ b2p,
    const void* __restrict__ ipwp, const void* __restrict__ ipbp,
    const void* __restrict__ w2p,
    float* __restrict__ W2KT, float* __restrict__ W2VT,
    u32* __restrict__ KB, u32* __restrict__ VB)
{
  if (sniff_bf16((const u32*)nfp) != BF16) return;

  __shared__ __align__(16) u32 fbS[64][66];   // (feats+b2) bf16-pairs [j][mw]
  __shared__ __align__(16) u32 wS[64][66];    // Wk-or-Wv half rows [chl][mw]
  __shared__ __align__(16) u32 w2S[128][33];  // W2 bf16 e-pairs [m][ew]
  const int tid = threadIdx.x;
  const int s = blockIdx.x >> 1, hf = blockIdx.x & 1;

  for (int idx = tid; idx < 4096; idx += 256) {
    int j = idx >> 6, mw = idx & 63;
    float2 f = ld2f<BF16>(nfp, ((s << 6) + j) * 64 + mw);
    float2 b = ld2f<BF16>(b2p, mw);
    fbS[j][mw] = pk(f.x + b.x, f.y + b.y);
  }
  for (int idx = tid; idx < 4096; idx += 256) {
    int chl = idx >> 6, mw = idx & 63;
    float2 wv = ld2f<BF16>(ipwp, (128 + hf * 64 + chl) * 64 + mw);  // Wk rows
    wS[chl][mw] = pk(wv.x, wv.y);
  }
  if (s < 16) {
    for (int idx = tid; idx < 4096; idx += 256) {
      int m = idx >> 5, ew = idx & 31;
      float2 wv = ld2f<BF16>(w2p, m * 32 + ew);
      w2S[m][ew] = pk(wv.x, wv.y);
    }
  }
  __syncthreads();

  const int cg = tid >> 6, lane = tid & 63;
  // kbase half -> KB
  {
    u32* dst = &KB[((s << 6) + lane) * 64 + hf * 32 + cg * 8];
    for (int p = 0; p < 8; ++p) {
      int chl = cg * 16 + 2 * p;
      float a0 = ld1f<BF16>(ipbp, 128 + hf * 64 + chl);
      float a1 = ld1f<BF16>(ipbp, 128 + hf * 64 + chl + 1);
      #pragma unroll 16
      for (int mw = 0; mw < 64; ++mw) {
        u32 fu = fbS[lane][mw];
        u32 w0 = wS[chl][mw], w1 = wS[chl + 1][mw];
        a0 = fmaf(bl(w0), bl(fu), a0); a0 = fmaf(bh(w0), bh(fu), a0);
        a1 = fmaf(bl(w1), bl(fu), a1); a1 = fmaf(bh(w1), bh(fu), a1);
      }
      dst[p] = pk(a0, a1);
    }
  }
  // W2KT slice (first 16 scenes' blocks; e = s*4+cg, ch = hf*64+lane)
  if (s < 16) {
    int e = s * 4 + cg;
    float acc = 0.f;
    #pragma unroll 16
    for (int mw = 0; mw < 64; ++mw) {
      u32 wu = wS[lane][mw];
      u32 u0 = w2S[2 * mw][e >> 1], u1 = w2S[2 * mw + 1][e >> 1];
      float x0 = (e & 1) ? bh(u0) : bl(u0);
      float x1 = (e & 1) ? bh(u1) : bl(u1);
      acc = fmaf(bl(wu), x0, acc);
      acc = fmaf(bh(wu), x1, acc);
    }
    W2KT[e * 128 + hf * 64 + lane] = acc;
  }
  __syncthreads();
  // reload with Wv, same dance
  for (int idx = tid; idx < 4096; idx += 256) {
    int chl = idx >> 6, mw = idx & 63;
    float2 wv = ld2f<BF16>(ipwp, (256 + hf * 64 + chl) * 64 + mw);
    wS[chl][mw] = pk(wv.x, wv.y);
  }
  __syncthreads();
  {
    u32* dst = &VB[((s << 6) + lane) * 64 + hf * 32 + cg * 8];
    for (int p = 0; p < 8; ++p) {
      int chl = cg * 16 + 2 * p;
      float a0 = ld1f<BF16>(ipbp, 256 + hf * 64 + chl);
      float a1 = ld1f<BF16>(ipbp, 256 + hf * 64 + chl + 1);
      #pragma unroll 16
      for (int mw = 0; mw < 64; ++mw) {
        u32 fu = fbS[lane][mw];
        u32 w0 = wS[chl][mw], w1 = wS[chl + 1][mw];
        a0 = fmaf(bl(w0), bl(fu), a0); a0 = fmaf(bh(w0), bh(fu), a0);
        a1 = fmaf(bl(w1), bl(fu), a1); a1 = fmaf(bh(w1), bh(fu), a1);
      }
      dst[p] = pk(a0, a1);
    }
  }
  if (s < 16) {
    int e = s * 4 + cg;
    float acc = 0.f;
    #pragma unroll 16
    for (int mw = 0; mw < 64; ++mw) {
      u32 wu = wS[lane][mw];
      u32 u0 = w2S[2 * mw][e >> 1], u1 = w2S[2 * mw + 1][e >> 1];
      float x0 = (e & 1) ? bh(u0) : bl(u0);
      float x1 = (e & 1) ? bh(u1) : bl(u1);
      acc = fmaf(bl(wu), x0, acc);
      acc = fmaf(bh(wu), x1, acc);
    }
    W2VT[e * 128 + hf * 64 + lane] = acc;
  }
}

// ---------------- kernel 2: fused attention, 1 block = (scene, 16 queries) --
template<bool BF16>
__global__ __launch_bounds__(256) void ee_main(
    const void* __restrict__ nfp, const void* __restrict__ posp,
    const void* __restrict__ w1p, const void* __restrict__ b1p,
    const void* __restrict__ ipwp, const void* __restrict__ ipbp,
    const void* __restrict__ owp, const void* __restrict__ obp,
    const void* __restrict__ pwp, const void* __restrict__ pbp,
    const float* __restrict__ W2KT, const float* __restrict__ W2VT,
    const u32* __restrict__ KB, const u32* __restrict__ VB,
    void* __restrict__ outp)
{
  if (sniff_bf16((const u32*)nfp) != BF16) return;

  __shared__ __align__(16) u32 kbS[64][66];
  __shared__ __align__(16) u32 vbS[64][66];
  __shared__ __align__(16) float2 posS[64];
  __shared__ __align__(16) float2 w1S[64];
  __shared__ __align__(16) float b1S[64];
  __shared__ __align__(16) float bqS[128], obS[128], pbS[128];
  __shared__ __align__(16) float fqS[4][128];     // feats[i] per wave
  __shared__ __align__(16) float qvS[4][128];     // q[i]
  __shared__ __align__(16) float qwS[4][4 * 64];  // [hd][e]
  __shared__ __align__(16) float4 atS[4][64];     // attn (4 heads) per j
  __shared__ __align__(16) float whS[4][4 * 64];  // [e*4+hd]
  __shared__ __align__(16) float ctxS[4][128];
  __shared__ __align__(16) float aoS[4][128];

  const int tid = threadIdx.x;
  const int s = blockIdx.x >> 2, qt = blockIdx.x & 3;
  const int w = tid >> 6, l = tid & 63;

  {
    const int sb = (s << 6) * 64;
    for (int idx = tid; idx < 4096; idx += 256) kbS[idx >> 6][idx & 63] = KB[sb + idx];
    for (int idx = tid; idx < 4096; idx += 256) vbS[idx >> 6][idx & 63] = VB[sb + idx];
    if (tid < 64) {
      posS[tid] = ld2f<BF16>(posp, (s << 6) + tid);
      w1S[tid]  = ld2f<BF16>(w1p, tid);
      b1S[tid]  = ld1f<BF16>(b1p, tid);
    } else if (tid < 192) {
      int c = tid - 64;
      bqS[c] = ld1f<BF16>(ipbp, c);
      obS[c] = ld1f<BF16>(obp, c);
      pbS[c] = ld1f<BF16>(pbp, c);
    }
  }
  __syncthreads();

  #pragma unroll 1
  for (int t = 0; t < 4; ++t) {
    const int il = qt * 16 + w + 4 * t;
    const int ig = (s << 6) + il;

    // S1: feats[i] -> fqS
    *(float2*)&fqS[w][2 * l] = ld2f<BF16>(nfp, ig * 64 + l);
    __syncthreads();
    // S2: q = Wq @ feats[i] + bq   (lane -> channels 2l,2l+1)
    {
      const int c0 = 2 * l;
      float a0 = bqS[c0], a1 = bqS[c0 + 1];
      #pragma unroll 4
      for (int cb = 0; cb < 16; ++cb) {
        float4 wa, wb, xa, xb;
        float4 f0 = *(const float4*)&fqS[w][8 * cb];
        float4 f1 = *(const float4*)&fqS[w][8 * cb + 4];
        ld8f<BF16>(ipwp, c0 * 16 + cb, wa, wb);
        ld8f<BF16>(ipwp, (c0 + 1) * 16 + cb, xa, xb);
        a0 = dot8(wa, wb, f0, f1, a0);
        a1 = dot8(xa, xb, f0, f1, a1);
      }
      *(float2*)&qvS[w][c0] = make_float2(a0, a1);
    }
    __syncthreads();
    // S4: qw[hd][e] = q_hd . W2k[:,e]_hd   (lane = e)
    {
      const float4* wk4 = (const float4*)W2KT;
      #pragma unroll
      for (int hd = 0; hd < 4; ++hd) {
        float acc = 0.f;
        #pragma unroll
        for (int dq = 0; dq < 8; ++dq) {
          float4 g = wk4[l * 32 + hd * 8 + dq];
          float4 qf = *(const float4*)&qvS[w][hd * 32 + 4 * dq];
          acc = fmaf(g.x, qf.x, acc); acc = fmaf(g.y, qf.y, acc);
          acc = fmaf(g.z, qf.z, acc); acc = fmaf(g.w, qf.w, acc);
        }
        qwS[w][hd * 64 + l] = acc;
      }
    }
    __syncthreads();
    // S5: hid + scores + softmax  (lane = j)
    {
      float hid[64];
      float2 pj = posS[l], pi = posS[il];
      float rx = pj.x - pi.x, ry = pj.y - pi.y;
      #pragma unroll
      for (int e = 0; e < 64; ++e) {
        float2 wv = w1S[e];
        hid[e] = fmaxf(0.f, fmaf(rx, wv.x, fmaf(ry, wv.y, b1S[e])));
      }
      float sc[4];
      #pragma unroll
      for (int hd = 0; hd < 4; ++hd) {
        float acc = 0.f;
        #pragma unroll 8
        for (int cw = hd * 16; cw < hd * 16 + 16; ++cw) {
          u32 u = kbS[l][cw];
          float2 qp = *(const float2*)&qvS[w][2 * cw];
          acc = fmaf(bl(u), qp.x, acc);
          acc = fmaf(bh(u), qp.y, acc);
        }
        #pragma unroll
        for (int e4 = 0; e4 < 16; ++e4) {
          float4 qq = *(const float4*)&qwS[w][hd * 64 + 4 * e4];
          acc = fmaf(qq.x, hid[4 * e4 + 0], acc);
          acc = fmaf(qq.y, hid[4 * e4 + 1], acc);
          acc = fmaf(qq.z, hid[4 * e4 + 2], acc);
          acc = fmaf(qq.w, hid[4 * e4 + 3], acc);
        }
        sc[hd] = acc * SCALE;
      }
      float at[4];
      #pragma unroll
      for (int hd = 0; hd < 4; ++hd) {
        float m = sc[hd];
        #pragma unroll
        for (int off = 32; off > 0; off >>= 1) m = fmaxf(m, __shfl_xor(m, off));
        float p = __expf(sc[hd] - m);
        float su = p;
        #pragma unroll
        for (int off = 32; off > 0; off >>= 1) su += __shfl_xor(su, off);
        at[hd] = p / su;
      }
      atS[w][l] = make_float4(at[0], at[1], at[2], at[3]);
    }
    __syncthreads();
    // S6: whid[hd][e] = sum_j attn[hd][j]*hid[j][e]  (lane = e, recompute hid)
    {
      float2 wv = w1S[l]; float b = b1S[l];
      float2 pi = posS[il];
      float wh0 = 0, wh1 = 0, wh2 = 0, wh3 = 0;
      #pragma unroll 8
      for (int j = 0; j < 64; ++j) {
        float2 pj = posS[j];
        float h = fmaxf(0.f, fmaf(pj.x - pi.x, wv.x, fmaf(pj.y - pi.y, wv.y, b)));
        float4 a = atS[w][j];
        wh0 = fmaf(a.x, h, wh0); wh1 = fmaf(a.y, h, wh1);
        wh2 = fmaf(a.z, h, wh2); wh3 = fmaf(a.w, h, wh3);
      }
      *(float4*)&whS[w][4 * l] = make_float4(wh0, wh1, wh2, wh3);
    }
    __syncthreads();
    // S7: ctx  (lane -> channels 2l,2l+1; head = l>>4)
    {
      const int hd = l >> 4;
      const float* atF = (const float*)&atS[w][0];
      float a0 = 0.f, a1 = 0.f;
      #pragma unroll 8
      for (int e = 0; e < 64; ++e) {
        float wh = whS[w][4 * e + hd];
        float2 g = *(const float2*)&W2VT[e * 128 + 2 * l];
        a0 = fmaf(wh, g.x, a0);
        a1 = fmaf(wh, g.y, a1);
      }
      #pragma unroll 8
      for (int j = 0; j < 64; ++j) {
        float a = atF[4 * j + hd];
        u32 u = vbS[j][l];
        a0 = fmaf(a, bl(u), a0);
        a1 = fmaf(a, bh(u), a1);
      }
      *(float2*)&ctxS[w][2 * l] = make_float2(a0, a1);
    }
    __syncthreads();
    // S8: attn_out = out_w @ ctx + out_b
    {
      const int c0 = 2 * l;
      float a0 = obS[c0], a1 = obS[c0 + 1];
      #pragma unroll 4
      for (int cb = 0; cb < 16; ++cb) {
        float4 wa, wb, xa, xb;
        float4 f0 = *(const float4*)&ctxS[w][8 * cb];
        float4 f1 = *(const float4*)&ctxS[w][8 * cb + 4];
        ld8f<BF16>(owp, c0 * 16 + cb, wa, wb);
        ld8f<BF16>(owp, (c0 + 1) * 16 + cb, xa, xb);
        a0 = dot8(wa, wb, f0, f1, a0);
        a1 = dot8(xa, xb, f0, f1, a1);
      }
      *(float2*)&aoS[w][c0] = make_float2(a0, a1);
    }
    __syncthreads();
    // S9: out = proj_w @ [feats; attn_out] + proj_b  -> d_out
    {
      const int c0 = 2 * l;
      float a0 = pbS[c0], a1 = pbS[c0 + 1];
      #pragma unroll 4
      for (int cb = 0; cb < 16; ++cb) {
        float4 wa, wb, xa, xb;
        float4 f0 = *(const float4*)&fqS[w][8 * cb];
        float4 f1 = *(const float4*)&fqS[w][8 * cb + 4];
        ld8f<BF16>(pwp, c0 * 32 + cb, wa, wb);
        ld8f<BF16>(pwp, (c0 + 1) * 32 + cb, xa, xb);
        a0 = dot8(wa, wb, f0, f1, a0);
        a1 = dot8(xa, xb, f0, f1, a1);
      }
      #pragma unroll 4
      for (int cb = 0; cb < 16; ++cb) {
        float4 wa, wb, xa, xb;
        float4 f0 = *(const float4*)&aoS[w][8 * cb];
        float4 f1 = *(const float4*)&aoS[w][8 * cb + 4];
        ld8f<BF16>(pwp, c0 * 32 + 16 + cb, wa, wb);
        ld8f<BF16>(pwp, (c0 + 1) * 32 + 16 + cb, xa, xb);
        a0 = dot8(wa, wb, f0, f1, a0);
        a1 = dot8(xa, xb, f0, f1, a1);
      }
      if (BF16) {
        ((u32*)outp)[ig * 64 + l] = pk(a0, a1);
      } else {
        ((float2*)outp)[ig * 64 + l] = make_float2(a0, a1);
      }
    }
    __syncthreads();
  }
}

extern "C" void kernel_launch(void* const* d_in, const int* in_sizes, int n_in,
                              void* d_out, int out_size, void* d_ws, size_t ws_size,
                              hipStream_t stream) {
  (void)in_sizes; (void)n_in; (void)out_size; (void)ws_size;
  const void* nfp  = d_in[0];
  const void* posp = d_in[1];
  const void* w1p  = d_in[2];
  const void* b1p  = d_in[3];
  const void* w2p  = d_in[4];
  const void* b2p  = d_in[5];
  const void* ipwp = d_in[6];
  const void* ipbp = d_in[7];
  const void* owp  = d_in[8];
  const void* obp  = d_in[9];
  const void* pwp  = d_in[10];
  const void* pbp  = d_in[11];

  char* ws = (char*)d_ws;
  float* W2KT = (float*)ws;
  float* W2VT = (float*)(ws + 32768);
  u32* KB = (u32*)(ws + 65536);
  u32* VB = (u32*)(ws + 65536 + SNUM * 4096 * 4);

  ee_setup<true ><<<dim3(256), dim3(256), 0, stream>>>(nfp, b2p, ipwp, ipbp, w2p, W2KT, W2VT, KB, VB);
  ee_setup<false><<<dim3(256), dim3(256), 0, stream>>>(nfp, b2p, ipwp, ipbp, w2p, W2KT, W2VT, KB, VB);
  ee_main<true ><<<dim3(512), dim3(256), 0, stream>>>(nfp, posp, w1p, b1p, ipwp, ipbp,
                                                      owp, obp, pwp, pbp,
                                                      W2KT, W2VT, KB, VB, d_out);
  ee_main<false><<<dim3(512), dim3(256), 0, stream>>>(nfp, posp, w1p, b1p, ipwp, ipbp,
                                                      owp, obp, pwp, pbp,
                                                      W2KT, W2VT, KB, VB, d_out);
}

// Round 3
// 256.264 us; speedup vs baseline: 1.8674x; 1.8674x over previous
//
#include <hip/hip_runtime.h>
#include <hip/hip_bf16.h>

// EdgeEncoder — fp32 inputs (confirmed: bf16 interpretation NaN'd in R1,
// dual-variant R2 passed => fp32 path was live). Internal bf16 staging.
//
// Algebraic folding:
//   k[i,j] = kbase[j] + W2k @ hid[i,j],   W2k = Wk @ W2 (128x64)
//   score  = q.kbase[j] + qw[i,hd].hid[i,j]
//   ctx    = sum_j attn*vbase[j] + W2v @ (sum_j attn*hid[i,j])
//
// R3: wave-synchronous main kernel (no per-stage __syncthreads; per-wave
// lgkmcnt drain only), 512-thr blocks (8 waves = 8 queries), 16 waves/CU,
// VGPR<=128 via hid chunking, bf16-packed weights in ws.
//
// ws layout (bytes):
//   [0,16K)      W2KB  u32 [e][cw]      (Wk@W2, bf16 pairs)
//   [16K,32K)    W2VB  u32 [e][cw]
//   [32K,64K)    WQB   u32 [c][mw]      Wq bf16 pairs (128x64 u32)
//   [64K,96K)    OWB   u32 [c][mw]      out_w
//   [96K,160K)   PWB   u32 [c][mw]      proj_w (128x128 u32)
//   [160K,+2M)   KB    u32 [s][j][cw]   kbase bf16 pairs
//   [+2M,+4M)    VB    u32 [s][j][cw]   vbase

typedef unsigned int u32;
#define SCALE 0.17677669529663689f   // 1/sqrt(32)

__device__ __forceinline__ float bl(u32 u){ union{u32 x; float f;} c; c.x = u << 16; return c.f; }
__device__ __forceinline__ float bh(u32 u){ union{u32 x; float f;} c; c.x = u & 0xffff0000u; return c.f; }
__device__ __forceinline__ u32 pk(float a, float b){
  union{float f; u32 x;} ca, cb; ca.f = a; cb.f = b;
  u32 ua = (ca.x + 0x7fffu + ((ca.x >> 16) & 1u)) >> 16;   // RNE fp32->bf16
  u32 ub = (cb.x + 0x7fffu + ((cb.x >> 16) & 1u)) >> 16;
  return ua | (ub << 16);
}
__device__ __forceinline__ float dot8(uint4 u, float4 f0, float4 f1, float acc){
  acc = fmaf(bl(u.x), f0.x, acc); acc = fmaf(bh(u.x), f0.y, acc);
  acc = fmaf(bl(u.y), f0.z, acc); acc = fmaf(bh(u.y), f0.w, acc);
  acc = fmaf(bl(u.z), f1.x, acc); acc = fmaf(bh(u.z), f1.y, acc);
  acc = fmaf(bl(u.w), f1.z, acc); acc = fmaf(bh(u.w), f1.w, acc);
  return acc;
}
// wave-local sync: drain LDS ops (lgkmcnt(0) only; vmcnt/expcnt unconstrained)
// + compiler scheduling fence. Same-wave cross-lane LDS RAW is safe after this.
__device__ __forceinline__ void wsync(){
  __builtin_amdgcn_s_waitcnt(0xC07F);
  __builtin_amdgcn_wave_barrier();
}

// ---------------- kernel 1: bases + folded matrices + weight packing -------
// grid 512: b = s*4 + hf*2 + pg. s=scene, hf=channel half, pg=p-quarter pair.
__global__ __launch_bounds__(256) void ee_setup(
    const float* __restrict__ nf, const float* __restrict__ b2,
    const float* __restrict__ ipw, const float* __restrict__ ipb,
    const float* __restrict__ w2,
    const float* __restrict__ ow, const float* __restrict__ pw,
    u32* __restrict__ W2KB, u32* __restrict__ W2VB,
    u32* __restrict__ WQB, u32* __restrict__ OWB, u32* __restrict__ PWB,
    u32* __restrict__ KB, u32* __restrict__ VB)
{
  __shared__ __align__(16) u32 fbS[64][66];   // (feats+b2) bf16-pairs [j][mw]
  __shared__ __align__(16) u32 wS[64][66];    // Wk-or-Wv half rows [chl][mw]
  __shared__ __align__(16) u32 w2S[128][33];  // W2 bf16 e-pairs [m][ew]
  const int tid = threadIdx.x;
  const int b = blockIdx.x;
  const int s = b >> 2, hf = (b >> 1) & 1, pg = b & 1;
  const float2* nf2  = (const float2*)nf;
  const float2* b22  = (const float2*)b2;
  const float2* ipw2 = (const float2*)ipw;
  const float2* w22  = (const float2*)w2;
  const float2* ow2  = (const float2*)ow;
  const float2* pw2  = (const float2*)pw;

  // independent: pack attention/out/proj weights to bf16 (blocks s>=96)
  if (b >= 384) {
    int g = (b - 384) * 256 + tid;            // 0..32767, one u32 each
    if (g < 8192) {                            // WQB: Wq rows 0..127
      float2 f = ipw2[g];                      // row g>>6, pair g&63
      WQB[g] = pk(f.x, f.y);
    } else if (g < 16384) {
      int i = g - 8192; float2 f = ow2[i];
      OWB[i] = pk(f.x, f.y);
    } else {
      int i = g - 16384; float2 f = pw2[i];    // row i>>7, pair i&127
      PWB[i] = pk(f.x, f.y);
    }
  }

  for (int idx = tid; idx < 4096; idx += 256) {
    int j = idx >> 6, mw = idx & 63;
    float2 f = nf2[((s << 6) + j) * 64 + mw];
    float2 bb = b22[mw];
    fbS[j][mw] = pk(f.x + bb.x, f.y + bb.y);
  }
  for (int idx = tid; idx < 4096; idx += 256) {
    int chl = idx >> 6, mw = idx & 63;
    float2 wv = ipw2[(128 + hf * 64 + chl) * 64 + mw];   // Wk rows
    wS[chl][mw] = pk(wv.x, wv.y);
  }
  if (s < 16) {
    for (int idx = tid; idx < 4096; idx += 256) {
      int m = idx >> 5, ew = idx & 31;
      float2 wv = w22[m * 32 + ew];
      w2S[m][ew] = pk(wv.x, wv.y);
    }
  }
  __syncthreads();

  const int cg = tid >> 6, lane = tid & 63;
  // kbase quarter -> KB
  {
    u32* dst = &KB[((s << 6) + lane) * 64 + hf * 32 + cg * 8];
    for (int pp = 0; pp < 4; ++pp) {
      int p = pg * 4 + pp;
      int chl = cg * 16 + 2 * p;
      float a0 = ipb[128 + hf * 64 + chl];
      float a1 = ipb[128 + hf * 64 + chl + 1];
      #pragma unroll 16
      for (int mw = 0; mw < 64; ++mw) {
        u32 fu = fbS[lane][mw];
        u32 w0 = wS[chl][mw], w1 = wS[chl + 1][mw];
        a0 = fmaf(bl(w0), bl(fu), a0); a0 = fmaf(bh(w0), bh(fu), a0);
        a1 = fmaf(bl(w1), bl(fu), a1); a1 = fmaf(bh(w1), bh(fu), a1);
      }
      dst[p] = pk(a0, a1);
    }
  }
  // W2KB slice: e = s*4+cg, ch pair = hf*64 + 2c'
  if (s < 16 && pg == 0 && lane < 32) {
    int e = s * 4 + cg, c = lane;
    float a0 = 0.f, a1 = 0.f;
    #pragma unroll 16
    for (int mw = 0; mw < 64; ++mw) {
      u32 w0 = wS[2 * c][mw], w1 = wS[2 * c + 1][mw];
      u32 u0 = w2S[2 * mw][e >> 1], u1 = w2S[2 * mw + 1][e >> 1];
      float x0 = (e & 1) ? bh(u0) : bl(u0);
      float x1 = (e & 1) ? bh(u1) : bl(u1);
      a0 = fmaf(bl(w0), x0, a0); a0 = fmaf(bh(w0), x1, a0);
      a1 = fmaf(bl(w1), x0, a1); a1 = fmaf(bh(w1), x1, a1);
    }
    W2KB[e * 64 + hf * 32 + c] = pk(a0, a1);
  }
  __syncthreads();
  // restage with Wv
  for (int idx = tid; idx < 4096; idx += 256) {
    int chl = idx >> 6, mw = idx & 63;
    float2 wv = ipw2[(256 + hf * 64 + chl) * 64 + mw];
    wS[chl][mw] = pk(wv.x, wv.y);
  }
  __syncthreads();
  {
    u32* dst = &VB[((s << 6) + lane) * 64 + hf * 32 + cg * 8];
    for (int pp = 0; pp < 4; ++pp) {
      int p = pg * 4 + pp;
      int chl = cg * 16 + 2 * p;
      float a0 = ipb[256 + hf * 64 + chl];
      float a1 = ipb[256 + hf * 64 + chl + 1];
      #pragma unroll 16
      for (int mw = 0; mw < 64; ++mw) {
        u32 fu = fbS[lane][mw];
        u32 w0 = wS[chl][mw], w1 = wS[chl + 1][mw];
        a0 = fmaf(bl(w0), bl(fu), a0); a0 = fmaf(bh(w0), bh(fu), a0);
        a1 = fmaf(bl(w1), bl(fu), a1); a1 = fmaf(bh(w1), bh(fu), a1);
      }
      dst[p] = pk(a0, a1);
    }
  }
  if (s < 16 && pg == 1 && lane < 32) {
    int e = s * 4 + cg, c = lane;
    float a0 = 0.f, a1 = 0.f;
    #pragma unroll 16
    for (int mw = 0; mw < 64; ++mw) {
      u32 w0 = wS[2 * c][mw], w1 = wS[2 * c + 1][mw];
      u32 u0 = w2S[2 * mw][e >> 1], u1 = w2S[2 * mw + 1][e >> 1];
      float x0 = (e & 1) ? bh(u0) : bl(u0);
      float x1 = (e & 1) ? bh(u1) : bl(u1);
      a0 = fmaf(bl(w0), x0, a0); a0 = fmaf(bh(w0), x1, a0);
      a1 = fmaf(bl(w1), x0, a1); a1 = fmaf(bh(w1), x1, a1);
    }
    W2VB[e * 64 + hf * 32 + c] = pk(a0, a1);
  }
}

// ---------------- kernel 2: wave-synchronous fused attention ----------------
// grid 1024 x 512 thr: b = s*8 + oct; wave w handles query il = oct*8 + w.
__global__ __launch_bounds__(512, 4) void ee_main(
    const float* __restrict__ nf, const float* __restrict__ pos,
    const float* __restrict__ w1, const float* __restrict__ b1,
    const float* __restrict__ ipb,
    const float* __restrict__ ob, const float* __restrict__ pb,
    const u32* __restrict__ W2KB, const u32* __restrict__ W2VB,
    const u32* __restrict__ WQB, const u32* __restrict__ OWB,
    const u32* __restrict__ PWB,
    const u32* __restrict__ KB, const u32* __restrict__ VB,
    float* __restrict__ outp)
{
  __shared__ __align__(16) u32 kbS[64][66];
  __shared__ __align__(16) u32 vbS[64][66];
  __shared__ __align__(16) float2 posS[64];
  __shared__ __align__(16) float2 w1S[64];
  __shared__ __align__(16) float b1S[64];
  __shared__ __align__(16) float bqS[128], obS[128], pbS[128];
  __shared__ __align__(16) float fqS[8][128];   // feats[i]          (S1..S9)
  __shared__ __align__(16) float qcS[8][128];   // q (S2..S5) then ctx (S7..S8)
  __shared__ __align__(16) float qwS[8][256];   // qw[hd][e] (S4..S5) then ao (S8..S9)
  __shared__ __align__(16) float atS[8][256];   // attn [hd][j]      (S5..S7)
  __shared__ __align__(16) float whS[8][256];   // wh [hd][e]        (S6..S7)

  const int tid = threadIdx.x;
  const int s = blockIdx.x >> 3, oct = blockIdx.x & 7;
  const int w = tid >> 6, l = tid & 63;
  const int il = oct * 8 + w;
  const int ig = (s << 6) + il;

  {
    const int sb = (s << 6) * 64;
    for (int idx = tid; idx < 4096; idx += 512) kbS[idx >> 6][idx & 63] = KB[sb + idx];
    for (int idx = tid; idx < 4096; idx += 512) vbS[idx >> 6][idx & 63] = VB[sb + idx];
    if (tid < 64) {
      posS[tid] = ((const float2*)pos)[(s << 6) + tid];
      w1S[tid]  = ((const float2*)w1)[tid];
      b1S[tid]  = b1[tid];
    } else if (tid < 192) {
      int c = tid - 64;
      bqS[c] = ipb[c]; obS[c] = ob[c]; pbS[c] = pb[c];
    }
  }
  __syncthreads();
  // ---- from here: zero block barriers; each wave runs its query free ----

  // S1: feats[i] -> fqS
  *(float2*)&fqS[w][2 * l] = ((const float2*)nf)[ig * 64 + l];
  wsync();

  // S2: q = Wq @ feats + bq  (lane -> channels 2l, 2l+1)
  {
    const int c0 = 2 * l;
    float a0 = bqS[c0], a1 = bqS[c0 + 1];
    const uint4* W4 = (const uint4*)WQB;
    #pragma unroll 4
    for (int cb = 0; cb < 16; ++cb) {
      float4 f0 = *(const float4*)&fqS[w][8 * cb];
      float4 f1 = *(const float4*)&fqS[w][8 * cb + 4];
      a0 = dot8(W4[c0 * 16 + cb], f0, f1, a0);
      a1 = dot8(W4[(c0 + 1) * 16 + cb], f0, f1, a1);
    }
    *(float2*)&qcS[w][c0] = make_float2(a0, a1);
  }
  wsync();

  // S4: qw[hd][e] = q_hd . W2k[:,e]_hd   (lane = e)
  {
    const uint4* G4 = (const uint4*)W2KB;
    #pragma unroll
    for (int hd = 0; hd < 4; ++hd) {
      float acc = 0.f;
      #pragma unroll
      for (int k = 0; k < 4; ++k) {
        uint4 u = G4[l * 16 + hd * 4 + k];
        float4 q0 = *(const float4*)&qcS[w][hd * 32 + 8 * k];
        float4 q1 = *(const float4*)&qcS[w][hd * 32 + 8 * k + 4];
        acc = dot8(u, q0, q1, acc);
      }
      qwS[w][hd * 64 + l] = acc;
    }
  }
  wsync();

  // S5: scores + softmax  (lane = j; hid chunked by 16 to cap VGPRs)
  {
    float accs[4];
    #pragma unroll
    for (int hd = 0; hd < 4; ++hd) {
      float a = 0.f;
      #pragma unroll 16
      for (int m = 0; m < 16; ++m) {
        u32 u = kbS[l][hd * 16 + m];
        float2 qp = *(const float2*)&qcS[w][2 * (hd * 16 + m)];
        a = fmaf(bl(u), qp.x, a); a = fmaf(bh(u), qp.y, a);
      }
      accs[hd] = a;
    }
    float2 pi = posS[il], pj = posS[l];
    float rx = pj.x - pi.x, ry = pj.y - pi.y;
    #pragma unroll
    for (int eb = 0; eb < 4; ++eb) {
      float h[16];
      #pragma unroll
      for (int m = 0; m < 16; ++m) {
        float2 wv = w1S[eb * 16 + m];
        h[m] = fmaxf(0.f, fmaf(rx, wv.x, fmaf(ry, wv.y, b1S[eb * 16 + m])));
      }
      #pragma unroll
      for (int hd = 0; hd < 4; ++hd) {
        float a = accs[hd];
        #pragma unroll
        for (int m4 = 0; m4 < 4; ++m4) {
          float4 qq = *(const float4*)&qwS[w][hd * 64 + eb * 16 + 4 * m4];
          a = fmaf(qq.x, h[4 * m4 + 0], a); a = fmaf(qq.y, h[4 * m4 + 1], a);
          a = fmaf(qq.z, h[4 * m4 + 2], a); a = fmaf(qq.w, h[4 * m4 + 3], a);
        }
        accs[hd] = a;
      }
    }
    #pragma unroll
    for (int hd = 0; hd < 4; ++hd) {
      float sc = accs[hd] * SCALE;
      float m = sc;
      #pragma unroll
      for (int off = 32; off > 0; off >>= 1) m = fmaxf(m, __shfl_xor(m, off));
      float p = __expf(sc - m);
      float su = p;
      #pragma unroll
      for (int off = 32; off > 0; off >>= 1) su += __shfl_xor(su, off);
      atS[w][hd * 64 + l] = p / su;
    }
  }
  wsync();

  // S6: wh[hd][e] = sum_j attn[hd][j]*hid[j][e]  (lane = e, recompute hid)
  {
    float2 wv = w1S[l]; float bb = b1S[l];
    float2 pi = posS[il];
    float wh0 = 0.f, wh1 = 0.f, wh2 = 0.f, wh3 = 0.f;
    #pragma unroll 8
    for (int j = 0; j < 64; ++j) {
      float2 pj = posS[j];
      float h = fmaxf(0.f, fmaf(pj.x - pi.x, wv.x, fmaf(pj.y - pi.y, wv.y, bb)));
      wh0 = fmaf(atS[w][j],       h, wh0);
      wh1 = fmaf(atS[w][64 + j],  h, wh1);
      wh2 = fmaf(atS[w][128 + j], h, wh2);
      wh3 = fmaf(atS[w][192 + j], h, wh3);
    }
    whS[w][l] = wh0; whS[w][64 + l] = wh1;
    whS[w][128 + l] = wh2; whS[w][192 + l] = wh3;
  }
  wsync();

  // S7: ctx (lane -> channels 2l,2l+1; head = l>>4)
  {
    const int hd = l >> 4;
    float a0 = 0.f, a1 = 0.f;
    #pragma unroll 8
    for (int e = 0; e < 64; ++e) {
      float wh = whS[w][hd * 64 + e];
      u32 g = W2VB[e * 64 + l];
      a0 = fmaf(wh, bl(g), a0); a1 = fmaf(wh, bh(g), a1);
    }
    #pragma unroll 8
    for (int j = 0; j < 64; ++j) {
      float a = atS[w][hd * 64 + j];
      u32 u = vbS[j][l];
      a0 = fmaf(a, bl(u), a0); a1 = fmaf(a, bh(u), a1);
    }
    *(float2*)&qcS[w][2 * l] = make_float2(a0, a1);   // ctx overwrites q
  }
  wsync();

  // S8: attn_out = out_w @ ctx + out_b  -> qwS[0..127]
  {
    const int c0 = 2 * l;
    float a0 = obS[c0], a1 = obS[c0 + 1];
    const uint4* W4 = (const uint4*)OWB;
    #pragma unroll 4
    for (int cb = 0; cb < 16; ++cb) {
      float4 f0 = *(const float4*)&qcS[w][8 * cb];
      float4 f1 = *(const float4*)&qcS[w][8 * cb + 4];
      a0 = dot8(W4[c0 * 16 + cb], f0, f1, a0);
      a1 = dot8(W4[(c0 + 1) * 16 + cb], f0, f1, a1);
    }
    *(float2*)&qwS[w][c0] = make_float2(a0, a1);      // ao overwrites qw
  }
  wsync();

  // S9: out = proj_w @ [feats; attn_out] + proj_b  (fp32 out)
  {
    const int c0 = 2 * l;
    float a0 = pbS[c0], a1 = pbS[c0 + 1];
    const uint4* W4 = (const uint4*)PWB;
    #pragma unroll 4
    for (int cb = 0; cb < 16; ++cb) {
      float4 f0 = *(const float4*)&fqS[w][8 * cb];
      float4 f1 = *(const float4*)&fqS[w][8 * cb + 4];
      a0 = dot8(W4[c0 * 32 + cb], f0, f1, a0);
      a1 = dot8(W4[(c0 + 1) * 32 + cb], f0, f1, a1);
    }
    #pragma unroll 4
    for (int cb = 0; cb < 16; ++cb) {
      float4 f0 = *(const float4*)&qwS[w][8 * cb];
      float4 f1 = *(const float4*)&qwS[w][8 * cb + 4];
      a0 = dot8(W4[c0 * 32 + 16 + cb], f0, f1, a0);
      a1 = dot8(W4[(c0 + 1) * 32 + 16 + cb], f0, f1, a1);
    }
    ((float2*)outp)[ig * 64 + l] = make_float2(a0, a1);
  }
}

extern "C" void kernel_launch(void* const* d_in, const int* in_sizes, int n_in,
                              void* d_out, int out_size, void* d_ws, size_t ws_size,
                              hipStream_t stream) {
  (void)in_sizes; (void)n_in; (void)out_size; (void)ws_size;
  const float* nf  = (const float*)d_in[0];
  const float* pos = (const float*)d_in[1];
  const float* w1  = (const float*)d_in[2];
  const float* b1  = (const float*)d_in[3];
  const float* w2  = (const float*)d_in[4];
  const float* b2  = (const float*)d_in[5];
  const float* ipw = (const float*)d_in[6];
  const float* ipb = (const float*)d_in[7];
  const float* ow  = (const float*)d_in[8];
  const float* ob  = (const float*)d_in[9];
  const float* pw  = (const float*)d_in[10];
  const float* pb  = (const float*)d_in[11];

  char* ws = (char*)d_ws;
  u32* W2KB = (u32*)(ws);
  u32* W2VB = (u32*)(ws + (16 << 10));
  u32* WQB  = (u32*)(ws + (32 << 10));
  u32* OWB  = (u32*)(ws + (64 << 10));
  u32* PWB  = (u32*)(ws + (96 << 10));
  u32* KB   = (u32*)(ws + (160 << 10));
  u32* VB   = (u32*)(ws + (160 << 10) + (128 * 4096 * 4));

  ee_setup<<<dim3(512), dim3(256), 0, stream>>>(nf, b2, ipw, ipb, w2, ow, pw,
                                                W2KB, W2VB, WQB, OWB, PWB, KB, VB);
  ee_main<<<dim3(1024), dim3(512), 0, stream>>>(nf, pos, w1, b1, ipb, ob, pb,
                                                W2KB, W2VB, WQB, OWB, PWB,
                                                KB, VB, (float*)d_out);
}